// Round 5
// baseline (334.252 us; speedup 1.0000x reference)
//
#include <hip/hip_runtime.h>

typedef __bf16 bf16x8 __attribute__((ext_vector_type(8)));
typedef float f32x4 __attribute__((ext_vector_type(4)));
typedef unsigned short u16;
typedef u16 u16x8 __attribute__((ext_vector_type(8)));

__device__ __forceinline__ u16 f2bf(float f) {
  unsigned u = __builtin_bit_cast(unsigned, f);
  unsigned r = (u + 0x7fffu + ((u >> 16) & 1u)) >> 16;  // RNE
  return (u16)r;
}

__device__ __forceinline__ bf16x8 cvt8(float4 a, float4 b) {
  bf16x8 h;
  h[0] = (__bf16)a.x; h[1] = (__bf16)a.y; h[2] = (__bf16)a.z; h[3] = (__bf16)a.w;
  h[4] = (__bf16)b.x; h[5] = (__bf16)b.y; h[6] = (__bf16)b.z; h[7] = (__bf16)b.w;
  return h;
}

// async global->LDS, 16B per lane (dest = wave-uniform base + lane*16 in HW).
__device__ __forceinline__ void gld_lds16(const u16* g, u16* l) {
  __builtin_amdgcn_global_load_lds(
      (__attribute__((address_space(1))) void*)(g),
      (__attribute__((address_space(3))) void*)(l), 16, 0, 0);
}

// ---------------------------------------------------------------------------
// k_simf<KDIV>: partial-K GEMM.  Lp[kc][n][c][d] = scale * sum_{s in chunk kc}
// K[n,c,s]*Q[n,d,s].  128x128 tile, BK=64, 512 thr / 8 waves (2x4).
// KDIV=4 -> 1024 blocks = 4 blocks/CU = 32 waves/CU: cross-block phase
// diversity hides the global-load latency that stalled the KDIV=1 version.
// ---------------------------------------------------------------------------
template <int KDIV>
__global__ __launch_bounds__(512) void k_simf(const float* __restrict__ K,
                                              const float* __restrict__ Q,
                                              float* __restrict__ Lp) {
  __shared__ u16 sA[128 * 64];
  __shared__ u16 sB[128 * 64];
  constexpr int NB = 256 * KDIV;
  const int bid = blockIdx.x;
  const int sid = (bid & 7) * (NB / 8) + (bid >> 3);  // bijective XCD swizzle
  constexpr int PER_N = 16 * KDIV;
  const int n = sid / PER_N;
  const int rem = sid % PER_N;
  const int kc = rem >> 4;
  const int r2 = rem & 15;
  const int cy = r2 >> 2, dx = r2 & 3;
  const int t = threadIdx.x, lane = t & 63, wid = t >> 6;
  const int wr = wid >> 2, wc = wid & 3;  // 2x4 waves, wave tile 64x32
  const float scale = 0.04419417382415922f;  // 512^-0.5

  const float* Ab = K + ((size_t)n * 512 + cy * 128) * 4096 + kc * (4096 / KDIV);
  const float* Bb = Q + ((size_t)n * 512 + dx * 128) * 4096 + kc * (4096 / KDIV);

  const int r0 = t >> 3, col8 = (t & 7) << 3;
  const int swz = col8 ^ ((r0 & 7) << 3);  // (r0+64)&7 == r0&7
  u16* const wA0 = &sA[r0 * 64 + swz];
  u16* const wA1 = &sA[(r0 + 64) * 64 + swz];
  u16* const wB0 = &sB[r0 * 64 + swz];
  u16* const wB1 = &sB[(r0 + 64) * 64 + swz];

  float4 ra[4], rb[4];
  f32x4 acc[4][2] = {};

#define SIMF_LOAD(k0)                                                           \
  {                                                                             \
    const float* pa = Ab + (size_t)r0 * 4096 + (k0) + col8;                     \
    ra[0] = *(const float4*)pa;                                                 \
    ra[1] = *(const float4*)(pa + 4);                                           \
    ra[2] = *(const float4*)(pa + 64 * 4096);                                   \
    ra[3] = *(const float4*)(pa + 64 * 4096 + 4);                               \
    const float* pb = Bb + (size_t)r0 * 4096 + (k0) + col8;                     \
    rb[0] = *(const float4*)pb;                                                 \
    rb[1] = *(const float4*)(pb + 4);                                           \
    rb[2] = *(const float4*)(pb + 64 * 4096);                                   \
    rb[3] = *(const float4*)(pb + 64 * 4096 + 4);                               \
  }

#define SIMF_WRITE()                                                            \
  {                                                                             \
    *(bf16x8*)wA0 = cvt8(ra[0], ra[1]);                                         \
    *(bf16x8*)wA1 = cvt8(ra[2], ra[3]);                                         \
    *(bf16x8*)wB0 = cvt8(rb[0], rb[1]);                                         \
    *(bf16x8*)wB1 = cvt8(rb[2], rb[3]);                                         \
  }

#define SIMF_COMPUTE()                                                          \
  {                                                                             \
    _Pragma("unroll") for (int ki = 0; ki < 2; ++ki) {                          \
      bf16x8 a[4], b[2];                                                        \
      const int ce = ki * 32 + (lane >> 4) * 8;                                 \
      _Pragma("unroll") for (int mi = 0; mi < 4; ++mi) {                        \
        const int r = wr * 64 + mi * 16 + (lane & 15);                          \
        a[mi] = *(const bf16x8*)&sA[r * 64 + (ce ^ ((r & 7) << 3))];            \
      }                                                                         \
      _Pragma("unroll") for (int ni = 0; ni < 2; ++ni) {                        \
        const int r = wc * 32 + ni * 16 + (lane & 15);                          \
        b[ni] = *(const bf16x8*)&sB[r * 64 + (ce ^ ((r & 7) << 3))];            \
      }                                                                         \
      _Pragma("unroll") for (int mi = 0; mi < 4; ++mi)                          \
        _Pragma("unroll") for (int ni = 0; ni < 2; ++ni)                        \
          acc[mi][ni] = __builtin_amdgcn_mfma_f32_16x16x32_bf16(                \
              a[mi], b[ni], acc[mi][ni], 0, 0, 0);                              \
    }                                                                           \
  }

  constexpr int NSTEP = 64 / KDIV;
  SIMF_LOAD(0);
  for (int kt = 0; kt < NSTEP; ++kt) {
    SIMF_WRITE();
    __syncthreads();
    if (kt < NSTEP - 1) SIMF_LOAD((kt + 1) << 6);
    SIMF_COMPUTE();
    __syncthreads();
  }

  float* Lb = Lp + (size_t)kc * 16 * 512 * 512 + (size_t)n * 512 * 512;
  const int c0 = cy * 128, d0 = dx * 128;
#pragma unroll
  for (int mi = 0; mi < 4; ++mi)
#pragma unroll
    for (int ni = 0; ni < 2; ++ni) {
      int colo = d0 + wc * 32 + ni * 16 + (lane & 15);
#pragma unroll
      for (int j = 0; j < 4; ++j) {
        int rowo = c0 + wr * 64 + mi * 16 + ((lane >> 4) << 2) + j;
        Lb[(size_t)rowo * 512 + colo] = acc[mi][ni][j] * scale;
      }
    }
#undef SIMF_LOAD
#undef SIMF_WRITE
#undef SIMF_COMPUTE
}

// ---------------------------------------------------------------------------
// k_stats<KDIV>: sum KDIV partials, softmax over c (online max+sum), E bf16.
// ---------------------------------------------------------------------------
template <int KDIV>
__global__ __launch_bounds__(256) void k_stats(const float* __restrict__ Lp,
                                               u16* __restrict__ E) {
  __shared__ float redm[4][64];
  __shared__ float reds[4][64];
  const int n = blockIdx.y;
  const int d0 = blockIdx.x * 64;
  const int tx = threadIdx.x & 63, ty = threadIdx.x >> 6;
  const size_t CH = (size_t)16 * 512 * 512;
  const float* B = Lp + (size_t)n * 512 * 512 + d0 + tx;

  float m = -3.0e38f, s = 0.f;
  for (int c = ty; c < 512; c += 4) {
    float v = B[(size_t)c * 512];
#pragma unroll
    for (int q = 1; q < KDIV; ++q) v += B[q * CH + (size_t)c * 512];
    float nm = fmaxf(m, v);
    s = s * __expf(m - nm) + __expf(v - nm);
    m = nm;
  }
  redm[ty][tx] = m;
  reds[ty][tx] = s;
  __syncthreads();
  float M = fmaxf(fmaxf(redm[0][tx], redm[1][tx]), fmaxf(redm[2][tx], redm[3][tx]));
  float S = reds[0][tx] * __expf(redm[0][tx] - M) + reds[1][tx] * __expf(redm[1][tx] - M) +
            reds[2][tx] * __expf(redm[2][tx] - M) + reds[3][tx] * __expf(redm[3][tx] - M);
  const float si = 1.0f / S;

  u16* Eb = E + (size_t)n * 512 * 512 + d0 + tx;
  for (int c = ty; c < 512; c += 4) {
    float v = B[(size_t)c * 512];
#pragma unroll
    for (int q = 1; q < KDIV; ++q) v += B[q * CH + (size_t)c * 512];
    Eb[(size_t)c * 512] = f2bf(__expf(v - M) * si);
  }
}

// ---------------------------------------------------------------------------
// k_vt: Vt[n,s,d] = bf16(V[n,d,s]).  Tile: 128 d x 64 s, swizzled fp32 LDS.
// ---------------------------------------------------------------------------
__global__ __launch_bounds__(256) void k_vt(const float* __restrict__ V,
                                            u16* __restrict__ Vt) {
  __shared__ float lds[128 * 68];
  const int n = blockIdx.z, d0 = blockIdx.y * 128, s0 = blockIdx.x * 64;
  const int t = threadIdx.x;
  {
    const int dr0 = t >> 2, c16 = (t & 3) << 4;
#pragma unroll
    for (int p = 0; p < 2; ++p) {
      const int dr = dr0 + p * 64;
      const float* src = V + ((size_t)n * 512 + d0 + dr) * 4096 + s0 + c16;
      float4 v0 = *(const float4*)src;
      float4 v1 = *(const float4*)(src + 4);
      float4 v2 = *(const float4*)(src + 8);
      float4 v3 = *(const float4*)(src + 12);
      const int sw = ((dr >> 3) & 7) << 2;
      float* dl = &lds[dr * 68];
      *(float4*)(dl + ((c16 + 0) ^ sw)) = v0;
      *(float4*)(dl + ((c16 + 4) ^ sw)) = v1;
      *(float4*)(dl + ((c16 + 8) ^ sw)) = v2;
      *(float4*)(dl + ((c16 + 12) ^ sw)) = v3;
    }
  }
  __syncthreads();
  {
    const int sr0 = t >> 4, dcol = (t & 15) << 3;
#pragma unroll
    for (int p2 = 0; p2 < 4; ++p2) {
      const int sr = sr0 + p2 * 16;
      bf16x8 h;
#pragma unroll
      for (int j = 0; j < 8; ++j) {
        const int d = dcol + j;
        h[j] = (__bf16)lds[d * 68 + (sr ^ (((d >> 3) & 7) << 2))];
      }
      *(bf16x8*)(Vt + ((size_t)n * 4096 + s0 + sr) * 512 + d0 + dcol) = h;
    }
  }
}

// ---------------------------------------------------------------------------
// k_ctx2: out[n,c,s] = sum_d E[n,c,d]*Vt[n,s,d]
// 128x128 tile, BK=64 (8 K-steps), gld_lds staging, pre-swizzled source.
// ---------------------------------------------------------------------------
__global__ __launch_bounds__(256) void k_ctx2(const u16* __restrict__ E,
                                              const u16* __restrict__ Vt,
                                              float* __restrict__ O) {
  __shared__ u16 sA[128 * 64];
  __shared__ u16 sB[128 * 64];
  const int bid = blockIdx.x;
  const int sid = (bid & 7) * 256 + (bid >> 3);  // 2048 % 8 == 0, bijective
  const int n = sid >> 7;
  const int rem = sid & 127;
  const int cy = rem >> 5, sx = rem & 31;
  const int t = threadIdx.x, lane = t & 63, wid = t >> 6;
  const int wr = wid >> 1, wc = wid & 1;

  const u16* Ab = E + ((size_t)n * 512 + cy * 128) * 512;
  const u16* Bb = Vt + ((size_t)n * 4096 + sx * 128) * 512;
  const int srow0 = t >> 3;
  const int scol = ((t & 7) << 3) ^ ((srow0 & 7) << 3);
  f32x4 acc[4][4] = {};

  for (int kd = 0; kd < 512; kd += 64) {
#pragma unroll
    for (int p = 0; p < 4; ++p) {
      const int row = srow0 + p * 32;
      gld_lds16(Ab + (size_t)row * 512 + kd + scol, &sA[(p * 256 + (wid << 6)) * 8]);
      gld_lds16(Bb + (size_t)row * 512 + kd + scol, &sB[(p * 256 + (wid << 6)) * 8]);
    }
    __syncthreads();
#pragma unroll
    for (int ki = 0; ki < 2; ++ki) {
      bf16x8 a[4], b[4];
      const int ce = ki * 32 + (lane >> 4) * 8;
#pragma unroll
      for (int mi = 0; mi < 4; ++mi) {
        const int r = wr * 64 + mi * 16 + (lane & 15);
        a[mi] = *(const bf16x8*)&sA[r * 64 + (ce ^ ((r & 7) << 3))];
      }
#pragma unroll
      for (int ni = 0; ni < 4; ++ni) {
        const int r = wc * 64 + ni * 16 + (lane & 15);
        b[ni] = *(const bf16x8*)&sB[r * 64 + (ce ^ ((r & 7) << 3))];
      }
#pragma unroll
      for (int mi = 0; mi < 4; ++mi)
#pragma unroll
        for (int ni = 0; ni < 4; ++ni)
          acc[mi][ni] = __builtin_amdgcn_mfma_f32_16x16x32_bf16(a[mi], b[ni], acc[mi][ni], 0, 0, 0);
    }
    __syncthreads();
  }
  float* Ob = O + ((size_t)n * 512 + cy * 128) * 4096 + sx * 128;
#pragma unroll
  for (int mi = 0; mi < 4; ++mi)
#pragma unroll
    for (int ni = 0; ni < 4; ++ni) {
      int colo = wc * 64 + ni * 16 + (lane & 15);
#pragma unroll
      for (int j = 0; j < 4; ++j) {
        int rowo = wr * 64 + mi * 16 + ((lane >> 4) << 2) + j;
        Ob[(size_t)rowo * 4096 + colo] = acc[mi][ni][j];
      }
    }
}

extern "C" void kernel_launch(void* const* d_in, const int* in_sizes, int n_in,
                              void* d_out, int out_size, void* d_ws, size_t ws_size,
                              hipStream_t stream) {
  const float* Kp = (const float*)d_in[0];  // key
  const float* Vp = (const float*)d_in[1];  // value
  const float* Qp = (const float*)d_in[2];  // query
  float* Op = (float*)d_out;
  char* ws = (char*)d_ws;
  const size_t MB = 1024 * 1024;

  if (ws_size >= 136 * MB) {
    float* Lp = (float*)ws;            // 4 x 16 MiB partials
    u16* E = (u16*)(ws + 64 * MB);     // 8 MiB
    u16* Vt = (u16*)(ws + 72 * MB);    // 64 MiB

    k_simf<4><<<1024, 512, 0, stream>>>(Kp, Qp, Lp);
    k_vt<<<dim3(64, 4, 16), 256, 0, stream>>>(Vp, Vt);
    k_stats<4><<<dim3(8, 16), 256, 0, stream>>>(Lp, E);
    k_ctx2<<<2048, 256, 0, stream>>>(E, Vt, Op);
  } else if (ws_size >= 88 * MB) {
    float* Lp = (float*)ws;            // 16 MiB
    u16* E = (u16*)(ws + 16 * MB);     // 8 MiB
    u16* Vt = (u16*)(ws + 24 * MB);    // 64 MiB

    k_simf<1><<<256, 512, 0, stream>>>(Kp, Qp, Lp);
    k_vt<<<dim3(64, 4, 16), 256, 0, stream>>>(Vp, Vt);
    k_stats<1><<<dim3(8, 16), 256, 0, stream>>>(Lp, E);
    k_ctx2<<<2048, 256, 0, stream>>>(E, Vt, Op);
  }
}

// Round 7
// 283.286 us; speedup vs baseline: 1.1799x; 1.1799x over previous
//
#include <hip/hip_runtime.h>

typedef __bf16 bf16x8 __attribute__((ext_vector_type(8)));
typedef float f32x4 __attribute__((ext_vector_type(4)));
typedef unsigned short u16;
typedef u16 u16x8 __attribute__((ext_vector_type(8)));

__device__ __forceinline__ u16 f2bf(float f) {
  unsigned u = __builtin_bit_cast(unsigned, f);
  unsigned r = (u + 0x7fffu + ((u >> 16) & 1u)) >> 16;  // RNE
  return (u16)r;
}

__device__ __forceinline__ u16x8 cvt8u(float4 a, float4 b) {
  u16x8 h;
  h[0] = f2bf(a.x); h[1] = f2bf(a.y); h[2] = f2bf(a.z); h[3] = f2bf(a.w);
  h[4] = f2bf(b.x); h[5] = f2bf(b.y); h[6] = f2bf(b.z); h[7] = f2bf(b.w);
  return h;
}

// async global->LDS, 16B per lane (dest = wave-uniform base + lane*16 in HW).
__device__ __forceinline__ void gld_lds16(const u16* g, u16* l) {
  __builtin_amdgcn_global_load_lds(
      (__attribute__((address_space(1))) void*)(g),
      (__attribute__((address_space(3))) void*)(l), 16, 0, 0);
}

// ---------------------------------------------------------------------------
// k_cvt: fp32 -> bf16 cast for K (y=0) and Q (y=1). 16 elems/thread, no loop.
// ---------------------------------------------------------------------------
__global__ __launch_bounds__(256) void k_cvt(const float* __restrict__ K,
                                             const float* __restrict__ Q,
                                             u16* __restrict__ Kb,
                                             u16* __restrict__ Qb) {
  const float* src = blockIdx.y ? Q : K;
  u16* dst = blockIdx.y ? Qb : Kb;
  const size_t i = ((size_t)blockIdx.x * 256 + threadIdx.x) * 16;
  float4 a0 = *(const float4*)(src + i);
  float4 a1 = *(const float4*)(src + i + 4);
  float4 a2 = *(const float4*)(src + i + 8);
  float4 a3 = *(const float4*)(src + i + 12);
  *(u16x8*)(dst + i) = cvt8u(a0, a1);
  *(u16x8*)(dst + i + 8) = cvt8u(a2, a3);
}

// ---------------------------------------------------------------------------
// k_simk<KDIV>: Lp[kc][n][c][d] = scale * sum_{s in chunk kc} Kb[n,c,s]*Qb[n,d,s]
// bf16 inputs. 128x128 tile, BK=64, 512 thr / 8 waves (2x4, wave 64x32).
// Double-buffered gld_lds staging, XOR-swizzle via pre-swizzled global source.
// KDIV=2 -> 512 blocks = 2 blocks/CU = 16 waves/CU.  Lp lives in d_out.
// ---------------------------------------------------------------------------
template <int KDIV>
__global__ __launch_bounds__(512) void k_simk(const u16* __restrict__ Kb,
                                              const u16* __restrict__ Qb,
                                              float* __restrict__ Lp) {
  __shared__ u16 sA[2][128 * 64];
  __shared__ u16 sB[2][128 * 64];
  constexpr int NB = 256 * KDIV;
  const int bid = blockIdx.x;
  const int sid = (bid & 7) * (NB / 8) + (bid >> 3);  // bijective XCD swizzle
  constexpr int PER_N = 16 * KDIV;
  const int n = sid / PER_N;
  const int rem = sid % PER_N;
  const int kc = rem >> 4;
  const int r2 = rem & 15;
  const int cy = r2 >> 2, dx = r2 & 3;
  const int t = threadIdx.x, lane = t & 63, wid = t >> 6;
  const int wr = wid >> 2, wc = wid & 3;  // 2x4 waves, wave tile 64x32
  const float scale = 0.04419417382415922f;  // 512^-0.5

  const u16* Ab = Kb + ((size_t)n * 512 + cy * 128) * 4096 + kc * (4096 / KDIV);
  const u16* Bb = Qb + ((size_t)n * 512 + dx * 128) * 4096 + kc * (4096 / KDIV);
  f32x4 acc[4][2] = {};

  // staging: chunk = q*512 + t; LDS row = chunk>>3 = q*64 + (t>>3); col16 = t&7
  const int srow0 = t >> 3;
  const int scol = ((t & 7) << 3) ^ ((srow0 & 7) << 3);  // pre-swizzled source col

#define SIM_STAGE(buf, k0)                                                      \
  {                                                                             \
    _Pragma("unroll") for (int q = 0; q < 2; ++q) {                             \
      const int row = q * 64 + srow0;                                           \
      gld_lds16(Ab + (size_t)row * 4096 + (k0) + scol,                          \
                &sA[buf][(q * 512 + (wid << 6)) * 8]);                          \
      gld_lds16(Bb + (size_t)row * 4096 + (k0) + scol,                          \
                &sB[buf][(q * 512 + (wid << 6)) * 8]);                          \
    }                                                                           \
  }

#define SIM_COMPUTE(buf)                                                        \
  {                                                                             \
    _Pragma("unroll") for (int ki = 0; ki < 2; ++ki) {                          \
      bf16x8 a[4], b[2];                                                        \
      const int ce = ki * 32 + (lane >> 4) * 8;                                 \
      _Pragma("unroll") for (int mi = 0; mi < 4; ++mi) {                        \
        const int r = wr * 64 + mi * 16 + (lane & 15);                          \
        a[mi] = *(const bf16x8*)&sA[buf][r * 64 + (ce ^ ((r & 7) << 3))];       \
      }                                                                         \
      _Pragma("unroll") for (int ni = 0; ni < 2; ++ni) {                        \
        const int r = wc * 32 + ni * 16 + (lane & 15);                          \
        b[ni] = *(const bf16x8*)&sB[buf][r * 64 + (ce ^ ((r & 7) << 3))];       \
      }                                                                         \
      _Pragma("unroll") for (int mi = 0; mi < 4; ++mi)                          \
        _Pragma("unroll") for (int ni = 0; ni < 2; ++ni)                        \
          acc[mi][ni] = __builtin_amdgcn_mfma_f32_16x16x32_bf16(                \
              a[mi], b[ni], acc[mi][ni], 0, 0, 0);                              \
    }                                                                           \
  }

  constexpr int NSTEP = 64 / KDIV;
  SIM_STAGE(0, 0);
  __syncthreads();
  int cur = 0;
  for (int kt = 0; kt < NSTEP - 1; ++kt) {
    SIM_STAGE(cur ^ 1, (kt + 1) << 6);  // next tile in flight across compute
    SIM_COMPUTE(cur);
    __syncthreads();
    cur ^= 1;
  }
  SIM_COMPUTE(cur);

  float* Lb = Lp + ((size_t)kc * 16 + n) * 512 * 512;
  const int c0 = cy * 128, d0 = dx * 128;
#pragma unroll
  for (int mi = 0; mi < 4; ++mi)
#pragma unroll
    for (int ni = 0; ni < 2; ++ni) {
      int colo = d0 + wc * 32 + ni * 16 + (lane & 15);
#pragma unroll
      for (int j = 0; j < 4; ++j) {
        int rowo = c0 + wr * 64 + mi * 16 + ((lane >> 4) << 2) + j;
        Lb[(size_t)rowo * 512 + colo] = acc[mi][ni][j] * scale;
      }
    }
#undef SIM_STAGE
#undef SIM_COMPUTE
}

// ---------------------------------------------------------------------------
// k_stats<KDIV>: sum KDIV partials, softmax over c, write E bf16.
// Block = (n, 32 d's) x 8 c-stripes; grid (16,16) = 256 blocks.
// ---------------------------------------------------------------------------
template <int KDIV>
__global__ __launch_bounds__(256) void k_stats(const float* __restrict__ Lp,
                                               u16* __restrict__ E) {
  __shared__ float redm[8][32];
  __shared__ float reds[8][32];
  const int n = blockIdx.y;
  const int d0 = blockIdx.x * 32;
  const int tx = threadIdx.x & 31, ty = threadIdx.x >> 5;
  const size_t CH = (size_t)16 * 512 * 512;
  const float* B = Lp + (size_t)n * 512 * 512 + d0 + tx;

  float m = -3.0e38f, s = 0.f;
  for (int c = ty; c < 512; c += 8) {
    float v = B[(size_t)c * 512];
#pragma unroll
    for (int q = 1; q < KDIV; ++q) v += B[q * CH + (size_t)c * 512];
    float nm = fmaxf(m, v);
    s = s * __expf(m - nm) + __expf(v - nm);
    m = nm;
  }
  redm[ty][tx] = m;
  reds[ty][tx] = s;
  __syncthreads();
  float M = redm[0][tx];
#pragma unroll
  for (int q = 1; q < 8; ++q) M = fmaxf(M, redm[q][tx]);
  float S = 0.f;
#pragma unroll
  for (int q = 0; q < 8; ++q) S += reds[q][tx] * __expf(redm[q][tx] - M);
  const float si = 1.0f / S;

  u16* Eb = E + (size_t)n * 512 * 512 + d0 + tx;
  for (int c = ty; c < 512; c += 8) {
    float v = B[(size_t)c * 512];
#pragma unroll
    for (int q = 1; q < KDIV; ++q) v += B[q * CH + (size_t)c * 512];
    Eb[(size_t)c * 512] = f2bf(__expf(v - M) * si);
  }
}

// ---------------------------------------------------------------------------
// k_vt: Vt[n,s,d] = bf16(V[n,d,s]).  Tile: 128 d x 64 s, swizzled fp32 LDS.
// ---------------------------------------------------------------------------
__global__ __launch_bounds__(256) void k_vt(const float* __restrict__ V,
                                            u16* __restrict__ Vt) {
  __shared__ float lds[128 * 68];
  const int n = blockIdx.z, d0 = blockIdx.y * 128, s0 = blockIdx.x * 64;
  const int t = threadIdx.x;
  {
    const int dr0 = t >> 2, c16 = (t & 3) << 4;
#pragma unroll
    for (int p = 0; p < 2; ++p) {
      const int dr = dr0 + p * 64;
      const float* src = V + ((size_t)n * 512 + d0 + dr) * 4096 + s0 + c16;
      float4 v0 = *(const float4*)src;
      float4 v1 = *(const float4*)(src + 4);
      float4 v2 = *(const float4*)(src + 8);
      float4 v3 = *(const float4*)(src + 12);
      const int sw = ((dr >> 3) & 7) << 2;
      float* dl = &lds[dr * 68];
      *(float4*)(dl + ((c16 + 0) ^ sw)) = v0;
      *(float4*)(dl + ((c16 + 4) ^ sw)) = v1;
      *(float4*)(dl + ((c16 + 8) ^ sw)) = v2;
      *(float4*)(dl + ((c16 + 12) ^ sw)) = v3;
    }
  }
  __syncthreads();
  {
    const int sr0 = t >> 4, dcol = (t & 15) << 3;
#pragma unroll
    for (int p2 = 0; p2 < 4; ++p2) {
      const int sr = sr0 + p2 * 16;
      u16x8 h;
#pragma unroll
      for (int j = 0; j < 8; ++j) {
        const int d = dcol + j;
        h[j] = f2bf(lds[d * 68 + (sr ^ (((d >> 3) & 7) << 2))]);
      }
      *(u16x8*)(Vt + ((size_t)n * 4096 + s0 + sr) * 512 + d0 + dcol) = h;
    }
  }
}

// ---------------------------------------------------------------------------
// k_ctx2: out[n,c,s] = sum_d E[n,c,d]*Vt[n,s,d]
// 128x128 tile, BK=64 (8 K-steps), gld_lds staging, pre-swizzled source.
// ---------------------------------------------------------------------------
__global__ __launch_bounds__(256) void k_ctx2(const u16* __restrict__ E,
                                              const u16* __restrict__ Vt,
                                              float* __restrict__ O) {
  __shared__ u16 sA[128 * 64];
  __shared__ u16 sB[128 * 64];
  const int bid = blockIdx.x;
  const int sid = (bid & 7) * 256 + (bid >> 3);  // 2048 % 8 == 0, bijective
  const int n = sid >> 7;
  const int rem = sid & 127;
  const int cy = rem >> 5, sx = rem & 31;
  const int t = threadIdx.x, lane = t & 63, wid = t >> 6;
  const int wr = wid >> 1, wc = wid & 1;

  const u16* Ab = E + ((size_t)n * 512 + cy * 128) * 512;
  const u16* Bb = Vt + ((size_t)n * 4096 + sx * 128) * 512;
  const int srow0 = t >> 3;
  const int scol = ((t & 7) << 3) ^ ((srow0 & 7) << 3);
  f32x4 acc[4][4] = {};

  for (int kd = 0; kd < 512; kd += 64) {
#pragma unroll
    for (int p = 0; p < 4; ++p) {
      const int row = srow0 + p * 32;
      gld_lds16(Ab + (size_t)row * 512 + kd + scol, &sA[(p * 256 + (wid << 6)) * 8]);
      gld_lds16(Bb + (size_t)row * 512 + kd + scol, &sB[(p * 256 + (wid << 6)) * 8]);
    }
    __syncthreads();
#pragma unroll
    for (int ki = 0; ki < 2; ++ki) {
      bf16x8 a[4], b[4];
      const int ce = ki * 32 + (lane >> 4) * 8;
#pragma unroll
      for (int mi = 0; mi < 4; ++mi) {
        const int r = wr * 64 + mi * 16 + (lane & 15);
        a[mi] = *(const bf16x8*)&sA[r * 64 + (ce ^ ((r & 7) << 3))];
      }
#pragma unroll
      for (int ni = 0; ni < 4; ++ni) {
        const int r = wc * 64 + ni * 16 + (lane & 15);
        b[ni] = *(const bf16x8*)&sB[r * 64 + (ce ^ ((r & 7) << 3))];
      }
#pragma unroll
      for (int mi = 0; mi < 4; ++mi)
#pragma unroll
        for (int ni = 0; ni < 4; ++ni)
          acc[mi][ni] = __builtin_amdgcn_mfma_f32_16x16x32_bf16(a[mi], b[ni], acc[mi][ni], 0, 0, 0);
    }
    __syncthreads();
  }
  float* Ob = O + ((size_t)n * 512 + cy * 128) * 4096 + sx * 128;
#pragma unroll
  for (int mi = 0; mi < 4; ++mi)
#pragma unroll
    for (int ni = 0; ni < 4; ++ni) {
      int colo = wc * 64 + ni * 16 + (lane & 15);
#pragma unroll
      for (int j = 0; j < 4; ++j) {
        int rowo = wr * 64 + mi * 16 + ((lane >> 4) << 2) + j;
        Ob[(size_t)rowo * 4096 + colo] = acc[mi][ni][j];
      }
    }
}

extern "C" void kernel_launch(void* const* d_in, const int* in_sizes, int n_in,
                              void* d_out, int out_size, void* d_ws, size_t ws_size,
                              hipStream_t stream) {
  const float* Kp = (const float*)d_in[0];  // key
  const float* Vp = (const float*)d_in[1];  // value
  const float* Qp = (const float*)d_in[2];  // query
  float* Op = (float*)d_out;
  char* ws = (char*)d_ws;
  const size_t MB = 1024 * 1024;

  // Workspace (peak 128 MiB; we know ws >= 144 MiB works):
  //   Kb: ws+0,  64 MiB  (dead after k_simk; Vt aliases it)
  //   Qb: ws+64, 64 MiB  (dead after k_simk; E aliases it)
  // Lp (2x16 MiB fp32 partials) lives in d_out (128 MiB, dead until k_ctx2).
  if (ws_size < 128 * MB) return;
  u16* Kb = (u16*)ws;
  u16* Qb = (u16*)(ws + 64 * MB);
  u16* Vt = (u16*)ws;             // aliases Kb (dead)
  u16* E  = (u16*)(ws + 64 * MB); // aliases Qb (dead)
  float* Lp = Op;                 // scratch inside d_out

  k_cvt<<<dim3(8192, 2), 256, 0, stream>>>(Kp, Qp, Kb, Qb);
  k_simk<2><<<512, 512, 0, stream>>>(Kb, Qb, Lp);
  k_stats<2><<<dim3(16, 16), 256, 0, stream>>>(Lp, E);   // E over dead Qb
  k_vt<<<dim3(64, 4, 16), 256, 0, stream>>>(Vp, Vt);     // Vt over dead Kb
  k_ctx2<<<2048, 256, 0, stream>>>(E, Vt, Op);           // overwrites Lp region
}